// Round 4
// baseline (155.403 us; speedup 1.0000x reference)
//
#include <hip/hip_runtime.h>
#include <math.h>

// Problem constants (from reference): B=2, L=1024, D=256, P=32
#define B_ 2
#define L_ 1024
#define D_ 256
#define P_ 32
#define NROW (B_*L_)          // 2048 flattened (b,l) rows
#define C_ 16                 // L chunks for the scan
#define CL_ (L_/C_)           // 64 positions per chunk
#define PIF 3.14159265358979323846f

// Native clang vector types — required by __builtin_nontemporal_store
typedef float nvf4 __attribute__((ext_vector_type(4)));
typedef float nvf2 __attribute__((ext_vector_type(2)));

// ---------------------------------------------------------------------------
// Projection kernel, 768 blocks x 256 threads.
//  blocks [0, 512): values GEMM, 4 rows/block, K-SPLIT: quarter-wave q owns
//    k in [64q, 64q+64); manual 4-deep ILP on Wv loads (round-3 lesson:
//    pragma unroll did NOT create load ILP — VGPR=28 proved serial chains).
//  blocks [512, 768): phase GEMM, 8 rows x 32 p; manual 8-deep ILP on Wp
//    loads + float4 LDS x-reads; tanh -> phases, sincos -> phasors +
//    transposed copy for the fused scan:
//      mode 1: phasorT is float  cos-only  [bp*L + l]   (256 KB)
//      mode 0: phasorT is float2 (cos,sin) [bp*L + l]   (512 KB)
// phasorMode: 0 = float2 (cos,sin), 1 = cos only, 2 = skip. hasPT: write pT.
// NO flags / NO atomics anywhere — round-2 lesson: agent-scope acquire/release
// storms the non-coherent per-XCD L2s (239 us). Kernel-boundary order only.
// ---------------------------------------------------------------------------
__global__ __launch_bounds__(256) void k_proj3(
    const float* __restrict__ x, const float* __restrict__ Wp,
    const float* __restrict__ bp, const float* __restrict__ Wv,
    const float* __restrict__ bv, float* __restrict__ values,
    float* __restrict__ phases_out, float* __restrict__ phasor_out,
    float* __restrict__ phasorT, int phasorMode, int mode, int hasPT)
{
    __shared__ float smem[5120];                 // 20 KB carved below
    const int tid = threadIdx.x;

    if (blockIdx.x < NROW / 4) {
        // ---- values: rows [row0, row0+4), K-split ----
        const int row0 = blockIdx.x * 4;
        float*  xsv = smem;                      // 1024 floats (4 KB)
        float4* red = (float4*)(smem + 1024);    // 1024 float4 (16 KB)

        ((float4*)xsv)[tid] = ((const float4*)(x + (size_t)row0 * D_))[tid];
        __syncthreads();

        const int q  = tid >> 6;                 // k-quarter, wave-uniform
        const int c4 = tid & 63;                 // float4 column group
        const float4* Wv4 = (const float4*)Wv;
        float4 acc[4];
        #pragma unroll
        for (int r = 0; r < 4; ++r) acc[r] = make_float4(0.f, 0.f, 0.f, 0.f);

        const int k0 = q * 64;
        for (int kk = 0; kk < 64; kk += 4) {
            const int k = k0 + kk;
            // 4 independent 16B loads in flight (explicit regs)
            float4 w0 = Wv4[(k + 0) * 64 + c4];
            float4 w1 = Wv4[(k + 1) * 64 + c4];
            float4 w2 = Wv4[(k + 2) * 64 + c4];
            float4 w3 = Wv4[(k + 3) * 64 + c4];
            #pragma unroll
            for (int r = 0; r < 4; ++r) {
                float4 xv = *(const float4*)(xsv + r * D_ + k);  // ds_read_b128 bcast
                acc[r].x += xv.x*w0.x + xv.y*w1.x + xv.z*w2.x + xv.w*w3.x;
                acc[r].y += xv.x*w0.y + xv.y*w1.y + xv.z*w2.y + xv.w*w3.y;
                acc[r].z += xv.x*w0.z + xv.y*w1.z + xv.z*w2.z + xv.w*w3.z;
                acc[r].w += xv.x*w0.w + xv.y*w1.w + xv.z*w2.w + xv.w*w3.w;
            }
        }
        #pragma unroll
        for (int r = 0; r < 4; ++r) red[(r * 4 + q) * 64 + c4] = acc[r];
        __syncthreads();

        const int r2 = tid >> 6;                 // row this thread finalizes
        float4 s0 = red[(r2 * 4 + 0) * 64 + c4];
        float4 s1 = red[(r2 * 4 + 1) * 64 + c4];
        float4 s2 = red[(r2 * 4 + 2) * 64 + c4];
        float4 s3 = red[(r2 * 4 + 3) * 64 + c4];
        const float4 b4 = ((const float4*)bv)[c4];
        float4 out;
        out.x = s0.x + s1.x + s2.x + s3.x + b4.x;
        out.y = s0.y + s1.y + s2.y + s3.y + b4.y;
        out.z = s0.z + s1.z + s2.z + s3.z + b4.z;
        out.w = s0.w + s1.w + s2.w + s3.w + b4.w;
        ((float4*)values)[(size_t)(row0 + r2) * 64 + c4] = out;
    } else {
        // ---- phases/phasors: rows [row0, row0+8) ----
        const int row0 = (blockIdx.x - NROW / 4) * 8;
        float* xs = smem;                        // 2048 floats (8 KB)
        const float4* xg4 = (const float4*)(x + (size_t)row0 * D_);
        ((float4*)xs)[tid]       = xg4[tid];
        ((float4*)xs)[tid + 256] = xg4[tid + 256];
        __syncthreads();

        const int p  = tid & (P_ - 1);
        const int rr = tid >> 5;                 // 0..7
        const float* xr = xs + rr * D_;
        // Manual 8-deep ILP: 8 named Wp loads (one 128B L1-hot line each per
        // wave) + 2 float4 LDS x-reads per batch; 4 partial sums cut the
        // FMA dependence chain.
        float a0 = 0.f, a1 = 0.f, a2 = 0.f, a3 = 0.f;
        for (int k = 0; k < D_; k += 8) {
            float w0 = Wp[(k + 0) * P_ + p];
            float w1 = Wp[(k + 1) * P_ + p];
            float w2 = Wp[(k + 2) * P_ + p];
            float w3 = Wp[(k + 3) * P_ + p];
            float w4 = Wp[(k + 4) * P_ + p];
            float w5 = Wp[(k + 5) * P_ + p];
            float w6 = Wp[(k + 6) * P_ + p];
            float w7 = Wp[(k + 7) * P_ + p];
            float4 xA = *(const float4*)(xr + k);
            float4 xB = *(const float4*)(xr + k + 4);
            a0 += xA.x * w0; a1 += xA.y * w1; a2 += xA.z * w2; a3 += xA.w * w3;
            a0 += xB.x * w4; a1 += xB.y * w5; a2 += xB.z * w6; a3 += xB.w * w7;
        }
        float a = (a0 + a1) + (a2 + a3);
        float ph = tanhf(a + bp[p]) * PIF;
        const int row = row0 + rr;
        const int idx = row * P_ + p;
        phases_out[idx] = ph;
        float s, c;
        sincosf(ph, &s, &c);
        if (phasorMode == 0) {
            ((float2*)phasor_out)[idx] = make_float2(c, s);
        } else if (phasorMode == 1) {
            phasor_out[idx] = c;
        }
        if (hasPT) {
            const int b = row >> 10, l = row & (L_ - 1);
            const size_t ti = (size_t)(b * P_ + p) * L_ + l;
            if (mode == 1) phasorT[ti] = c;                       // cos only
            else ((float2*)phasorT)[ti] = make_float2(c, s);
        }
    }
}

// ---------------------------------------------------------------------------
// Fused partial+scan, NO inter-block sync. Block (b,p,c):
//  1. stage phasor prefix [0, l0+CL) into LDS (coalesced from phasorT)
//  2. lookback: carry = sum_{l<l0} phasor*v — redundant recompute from
//     L2-resident values; manual 8-deep ILP (round-3: VGPR=28 proved the
//     pragma-unroll version ran a serial ~200cy/iter load chain -> 67 us).
//  3. scan: 64-step running sum, nontemporal store, batched loads.
// mode 1 (harness-verified via WRITE_SIZE): real part only -> cos-only
// phasor, 2 FMA/elem. mode 0: float2 phasor, 4 FMA/elem.
// ---------------------------------------------------------------------------
__global__ __launch_bounds__(128) void k_scan_fused(
    const float* __restrict__ values, const float* __restrict__ phases,
    const float* __restrict__ phasorT, float* __restrict__ mem,
    int mode, int hasPT)
{
    const int blk = blockIdx.x;                  // b*P_*C_ + p*C_ + c
    const int c = blk & (C_ - 1);
    const int p = (blk >> 4) & (P_ - 1);
    const int b = blk >> 9;
    const int tid = threadIdx.x;                 // 0..127
    const int l0 = c * CL_;
    const int bp = b * P_ + p;
    const int nPre = l0 + CL_;                   // phasor prefix length (<=1024)

    __shared__ float2 pc2[L_];                   // 8 KB; mode1 uses first 4 KB
    float* pc1 = (float*)pc2;

    if (hasPT) {
        if (mode == 1) {
            const float4* src = (const float4*)(phasorT + (size_t)bp * L_);
            for (int i = tid; i < nPre / 4; i += 128)
                ((float4*)pc1)[i] = src[i];      // coalesced 512B/wave
        } else {
            const float4* src =
                (const float4*)((const float2*)phasorT + (size_t)bp * L_);
            for (int i = tid; i < nPre / 2; i += 128)
                ((float4*)pc2)[i] = src[i];
        }
    } else {
        for (int l = tid; l < nPre; l += 128) {
            float ph = phases[(b * L_ + l) * P_ + p];
            if (mode == 1) pc1[l] = __cosf(ph);
            else           pc2[l] = make_float2(__cosf(ph), __sinf(ph));
        }
    }
    __syncthreads();

    const float2* vp = (const float2*)(values + (size_t)b * L_ * D_) + tid;

    if (mode == 1) {
        // ---- lookback: l0 % 8 == 0 always; 8 loads in flight, dual accs ----
        float cxA = 0.f, cxB = 0.f, czA = 0.f, czB = 0.f;
        for (int l = 0; l < l0; l += 8) {
            float2 v0 = vp[(size_t)(l + 0) * (D_/2)];
            float2 v1 = vp[(size_t)(l + 1) * (D_/2)];
            float2 v2 = vp[(size_t)(l + 2) * (D_/2)];
            float2 v3 = vp[(size_t)(l + 3) * (D_/2)];
            float2 v4 = vp[(size_t)(l + 4) * (D_/2)];
            float2 v5 = vp[(size_t)(l + 5) * (D_/2)];
            float2 v6 = vp[(size_t)(l + 6) * (D_/2)];
            float2 v7 = vp[(size_t)(l + 7) * (D_/2)];
            float p0 = pc1[l + 0]; float p1 = pc1[l + 1];
            float p2 = pc1[l + 2]; float p3 = pc1[l + 3];
            float p4 = pc1[l + 4]; float p5 = pc1[l + 5];
            float p6 = pc1[l + 6]; float p7 = pc1[l + 7];
            cxA += p0 * v0.x; czA += p0 * v0.y;
            cxB += p1 * v1.x; czB += p1 * v1.y;
            cxA += p2 * v2.x; czA += p2 * v2.y;
            cxB += p3 * v3.x; czB += p3 * v3.y;
            cxA += p4 * v4.x; czA += p4 * v4.y;
            cxB += p5 * v5.x; czB += p5 * v5.y;
            cxA += p6 * v6.x; czA += p6 * v6.y;
            cxB += p7 * v7.x; czB += p7 * v7.y;
        }
        float cx = cxA + cxB, cz = czA + czB;

        // ---- scan + NT store: batches of 8, loads up front ----
        nvf2* dst = (nvf2*)mem + ((size_t)(b * L_ + l0) * P_ + p) * (D_/2) + tid;
        for (int i = 0; i < CL_; i += 8) {
            const int l = l0 + i;
            float2 v0 = vp[(size_t)(l + 0) * (D_/2)];
            float2 v1 = vp[(size_t)(l + 1) * (D_/2)];
            float2 v2 = vp[(size_t)(l + 2) * (D_/2)];
            float2 v3 = vp[(size_t)(l + 3) * (D_/2)];
            float2 v4 = vp[(size_t)(l + 4) * (D_/2)];
            float2 v5 = vp[(size_t)(l + 5) * (D_/2)];
            float2 v6 = vp[(size_t)(l + 6) * (D_/2)];
            float2 v7 = vp[(size_t)(l + 7) * (D_/2)];
            float p0 = pc1[l + 0]; float p1 = pc1[l + 1];
            float p2 = pc1[l + 2]; float p3 = pc1[l + 3];
            float p4 = pc1[l + 4]; float p5 = pc1[l + 5];
            float p6 = pc1[l + 6]; float p7 = pc1[l + 7];
            const size_t st = (size_t)P_ * (D_/2);   // row stride in float2
            nvf2 o;
            cx += p0 * v0.x; cz += p0 * v0.y; o.x = cx; o.y = cz;
            __builtin_nontemporal_store(o, dst + (i + 0) * st);
            cx += p1 * v1.x; cz += p1 * v1.y; o.x = cx; o.y = cz;
            __builtin_nontemporal_store(o, dst + (i + 1) * st);
            cx += p2 * v2.x; cz += p2 * v2.y; o.x = cx; o.y = cz;
            __builtin_nontemporal_store(o, dst + (i + 2) * st);
            cx += p3 * v3.x; cz += p3 * v3.y; o.x = cx; o.y = cz;
            __builtin_nontemporal_store(o, dst + (i + 3) * st);
            cx += p4 * v4.x; cz += p4 * v4.y; o.x = cx; o.y = cz;
            __builtin_nontemporal_store(o, dst + (i + 4) * st);
            cx += p5 * v5.x; cz += p5 * v5.y; o.x = cx; o.y = cz;
            __builtin_nontemporal_store(o, dst + (i + 5) * st);
            cx += p6 * v6.x; cz += p6 * v6.y; o.x = cx; o.y = cz;
            __builtin_nontemporal_store(o, dst + (i + 6) * st);
            cx += p7 * v7.x; cz += p7 * v7.y; o.x = cx; o.y = cz;
            __builtin_nontemporal_store(o, dst + (i + 7) * st);
        }
    } else {
        // mode 0: full complex. Batches of 4 with explicit loads.
        float4 carry = make_float4(0.f, 0.f, 0.f, 0.f);
        for (int l = 0; l < l0; l += 4) {
            float2 v0 = vp[(size_t)(l + 0) * (D_/2)];
            float2 v1 = vp[(size_t)(l + 1) * (D_/2)];
            float2 v2 = vp[(size_t)(l + 2) * (D_/2)];
            float2 v3 = vp[(size_t)(l + 3) * (D_/2)];
            float2 q0 = pc2[l + 0]; float2 q1 = pc2[l + 1];
            float2 q2 = pc2[l + 2]; float2 q3 = pc2[l + 3];
            carry.x += q0.x*v0.x + q1.x*v1.x + q2.x*v2.x + q3.x*v3.x;
            carry.y += q0.y*v0.x + q1.y*v1.x + q2.y*v2.x + q3.y*v3.x;
            carry.z += q0.x*v0.y + q1.x*v1.y + q2.x*v2.y + q3.x*v3.y;
            carry.w += q0.y*v0.y + q1.y*v1.y + q2.y*v2.y + q3.y*v3.y;
        }
        nvf4* dst = (nvf4*)mem + ((size_t)(b * L_ + l0) * P_ + p) * (D_/2) + tid;
        const size_t st = (size_t)P_ * (D_/2);
        for (int i = 0; i < CL_; i += 4) {
            const int l = l0 + i;
            float2 v0 = vp[(size_t)(l + 0) * (D_/2)];
            float2 v1 = vp[(size_t)(l + 1) * (D_/2)];
            float2 v2 = vp[(size_t)(l + 2) * (D_/2)];
            float2 v3 = vp[(size_t)(l + 3) * (D_/2)];
            float2 q0 = pc2[l + 0]; float2 q1 = pc2[l + 1];
            float2 q2 = pc2[l + 2]; float2 q3 = pc2[l + 3];
            nvf4 o;
            carry.x += q0.x*v0.x; carry.y += q0.y*v0.x;
            carry.z += q0.x*v0.y; carry.w += q0.y*v0.y;
            o.x = carry.x; o.y = carry.y; o.z = carry.z; o.w = carry.w;
            __builtin_nontemporal_store(o, dst + (i + 0) * st);
            carry.x += q1.x*v1.x; carry.y += q1.y*v1.x;
            carry.z += q1.x*v1.y; carry.w += q1.y*v1.y;
            o.x = carry.x; o.y = carry.y; o.z = carry.z; o.w = carry.w;
            __builtin_nontemporal_store(o, dst + (i + 1) * st);
            carry.x += q2.x*v2.x; carry.y += q2.y*v2.x;
            carry.z += q2.x*v2.y; carry.w += q2.y*v2.y;
            o.x = carry.x; o.y = carry.y; o.z = carry.z; o.w = carry.w;
            __builtin_nontemporal_store(o, dst + (i + 2) * st);
            carry.x += q3.x*v3.x; carry.y += q3.y*v3.x;
            carry.z += q3.x*v3.y; carry.w += q3.y*v3.y;
            o.x = carry.x; o.y = carry.y; o.z = carry.z; o.w = carry.w;
            __builtin_nontemporal_store(o, dst + (i + 3) * st);
        }
    }
}

extern "C" void kernel_launch(void* const* d_in, const int* in_sizes, int n_in,
                              void* d_out, int out_size, void* d_ws, size_t ws_size,
                              hipStream_t stream) {
    const float* x  = (const float*)d_in[0];
    const float* Wp = (const float*)d_in[1];
    const float* bp = (const float*)d_in[2];
    const float* Wv = (const float*)d_in[3];
    const float* bv = (const float*)d_in[4];
    float* out = (float*)d_out;

    const size_t nMemF = (size_t)2 * B_ * L_ * P_ * D_;  // 33554432 (interleaved)
    const size_t nMemR = (size_t)B_ * L_ * P_ * D_;      // 16777216 (real only)
    const size_t nPh   = (size_t)B_ * L_ * P_;           // 65536

    // Output layout mode by out_size. Round-2/3 counter evidence: scan
    // WRITE_SIZE = 64 MiB = nMemR*4B => harness runs mode 1.
    int mode; size_t memFloats;
    if ((size_t)out_size >= nMemF + 3 * nPh) { mode = 0; memFloats = nMemF; }
    else                                     { mode = 1; memFloats = nMemR; }
    const bool memFits      = (size_t)out_size >= memFloats;
    const bool phasesInOut  = (size_t)out_size >= memFloats + nPh;
    const bool phasorsInOut =
        (size_t)out_size >= memFloats + nPh + (mode == 0 ? 2 * nPh : nPh);

    // ws layout: values | phasesWs | phasorT
    const size_t valB = (size_t)B_ * L_ * D_ * sizeof(float);                // 2 MB
    const size_t phB  = nPh * sizeof(float);                                 // 256 KB
    const size_t ptB  = nPh * (mode == 0 ? sizeof(float2) : sizeof(float));  // 512/256 KB
    float* values   = (float*)d_ws;
    float* phasesWs = (float*)((char*)d_ws + valB);
    float* phasorT  = (float*)((char*)d_ws + valB + phB);

    float* phasesPtr = phasesInOut ? (out + memFloats)
                     : (ws_size >= valB + phB ? phasesWs : nullptr);
    if (phasesPtr == nullptr) return;            // unreachable (ws verified big enough)

    float* phasorPtr = phasorsInOut ? (out + memFloats + nPh) : nullptr;
    const int phasorMode = phasorsInOut ? mode : 2;

    const int hasPT = (ws_size >= valB + phB + ptB) ? 1 : 0;

    k_proj3<<<NROW / 4 + NROW / 8, 256, 0, stream>>>(
        x, Wp, bp, Wv, bv, values, phasesPtr, phasorPtr, phasorT,
        phasorMode, mode, hasPT);
    if (!memFits) return;

    k_scan_fused<<<B_ * P_ * C_, 128, 0, stream>>>(values, phasesPtr, phasorT,
                                                   out, mode, hasPT);
}

// Round 5
// 107.943 us; speedup vs baseline: 1.4397x; 1.4397x over previous
//
#include <hip/hip_runtime.h>
#include <math.h>

// Problem constants (from reference): B=2, L=1024, D=256, P=32
#define B_ 2
#define L_ 1024
#define D_ 256
#define P_ 32
#define NROW (B_*L_)          // 2048 flattened (b,l) rows
#define C_ 16                 // L chunks for the scan
#define CL_ (L_/C_)           // 64 positions per chunk
#define PIF 3.14159265358979323846f

// Native clang vector types — required by __builtin_nontemporal_store
typedef float nvf4 __attribute__((ext_vector_type(4)));
typedef float nvf2 __attribute__((ext_vector_type(2)));

// ---------------------------------------------------------------------------
// Projection kernel, 1280 blocks x 256 threads.
//  blocks [0, 1024): values GEMM, 2 rows/block (round-5: was 4 — halving rows
//    doubles block count -> 20 waves/CU for latency hiding; Wv L2 traffic
//    2x but ~8 us aggregate, hidden). K-SPLIT: quarter-wave q owns
//    k in [64q, 64q+64); partials reduced through 8 KB LDS.
//  blocks [1024, 1280): phase GEMM, 8 rows x 32 p; fast tanh via __expf and
//    __sincosf (round-5: absmax 0.25 is summation-order noise, 1e-6 phase
//    error invisible); phases -> out, phasors -> out, transposed phasor copy:
//      mode 1: phasorT is float  cos-only  [bp*L + l]   (256 KB)
//      mode 0: phasorT is float2 (cos,sin) [bp*L + l]   (512 KB)
// phasorMode: 0 = float2 (cos,sin), 1 = cos only, 2 = skip. hasPT: write pT.
// NO inter-block sync anywhere — round-2 lesson: agent-scope acquire/release
// storms the non-coherent per-XCD L2s (239 us). Round-4 lesson: triangular
// per-block work gives a latency-exposed tail (67-74 us) — keep work UNIFORM.
// ---------------------------------------------------------------------------
__global__ __launch_bounds__(256) void k_proj3(
    const float* __restrict__ x, const float* __restrict__ Wp,
    const float* __restrict__ bp, const float* __restrict__ Wv,
    const float* __restrict__ bv, float* __restrict__ values,
    float* __restrict__ phases_out, float* __restrict__ phasor_out,
    float* __restrict__ phasorT, int phasorMode, int mode, int hasPT)
{
    __shared__ float smem[2560];                 // 10 KB carved below
    const int tid = threadIdx.x;

    if (blockIdx.x < NROW / 2) {
        // ---- values: rows [row0, row0+2), K-split ----
        const int row0 = blockIdx.x * 2;
        float*  xsv = smem;                      // 512 floats (2 KB)
        float4* red = (float4*)(smem + 512);     // 512 float4 (8 KB)

        if (tid < 128)
            ((float4*)xsv)[tid] = ((const float4*)(x + (size_t)row0 * D_))[tid];
        __syncthreads();

        const int q  = tid >> 6;                 // k-quarter, wave-uniform
        const int c4 = tid & 63;                 // float4 column group
        const float4* Wv4 = (const float4*)Wv;
        float4 acc0 = make_float4(0.f, 0.f, 0.f, 0.f);
        float4 acc1 = make_float4(0.f, 0.f, 0.f, 0.f);

        const int k0 = q * 64;
        for (int kk = 0; kk < 64; kk += 4) {
            const int k = k0 + kk;
            float4 w0 = Wv4[(k + 0) * 64 + c4]; // coalesced 1KB/wave
            float4 w1 = Wv4[(k + 1) * 64 + c4];
            float4 w2 = Wv4[(k + 2) * 64 + c4];
            float4 w3 = Wv4[(k + 3) * 64 + c4];
            float4 xa = *(const float4*)(xsv + 0 * D_ + k);  // bcast b128
            float4 xb = *(const float4*)(xsv + 1 * D_ + k);
            acc0.x += xa.x*w0.x + xa.y*w1.x + xa.z*w2.x + xa.w*w3.x;
            acc0.y += xa.x*w0.y + xa.y*w1.y + xa.z*w2.y + xa.w*w3.y;
            acc0.z += xa.x*w0.z + xa.y*w1.z + xa.z*w2.z + xa.w*w3.z;
            acc0.w += xa.x*w0.w + xa.y*w1.w + xa.z*w2.w + xa.w*w3.w;
            acc1.x += xb.x*w0.x + xb.y*w1.x + xb.z*w2.x + xb.w*w3.x;
            acc1.y += xb.x*w0.y + xb.y*w1.y + xb.z*w2.y + xb.w*w3.y;
            acc1.z += xb.x*w0.z + xb.y*w1.z + xb.z*w2.z + xb.w*w3.z;
            acc1.w += xb.x*w0.w + xb.y*w1.w + xb.z*w2.w + xb.w*w3.w;
        }
        red[(0 * 4 + q) * 64 + c4] = acc0;
        red[(1 * 4 + q) * 64 + c4] = acc1;
        __syncthreads();

        if (tid < 128) {
            const int r2 = tid >> 6;             // row this thread finalizes
            const int cb = tid & 63;
            float4 s0 = red[(r2 * 4 + 0) * 64 + cb];
            float4 s1 = red[(r2 * 4 + 1) * 64 + cb];
            float4 s2 = red[(r2 * 4 + 2) * 64 + cb];
            float4 s3 = red[(r2 * 4 + 3) * 64 + cb];
            const float4 b4 = ((const float4*)bv)[cb];
            float4 o;
            o.x = s0.x + s1.x + s2.x + s3.x + b4.x;
            o.y = s0.y + s1.y + s2.y + s3.y + b4.y;
            o.z = s0.z + s1.z + s2.z + s3.z + b4.z;
            o.w = s0.w + s1.w + s2.w + s3.w + b4.w;
            ((float4*)values)[(size_t)(row0 + r2) * 64 + cb] = o;
        }
    } else {
        // ---- phases/phasors: rows [row0, row0+8) ----
        const int row0 = (blockIdx.x - NROW / 2) * 8;
        float* xs = smem;                        // 2048 floats (8 KB)
        const float4* xg4 = (const float4*)(x + (size_t)row0 * D_);
        ((float4*)xs)[tid]       = xg4[tid];
        ((float4*)xs)[tid + 256] = xg4[tid + 256];
        __syncthreads();

        const int p  = tid & (P_ - 1);
        const int rr = tid >> 5;                 // 0..7
        const float* xr = xs + rr * D_;
        float a0 = 0.f, a1 = 0.f, a2 = 0.f, a3 = 0.f;
        for (int k = 0; k < D_; k += 8) {
            float w0 = Wp[(k + 0) * P_ + p];
            float w1 = Wp[(k + 1) * P_ + p];
            float w2 = Wp[(k + 2) * P_ + p];
            float w3 = Wp[(k + 3) * P_ + p];
            float w4 = Wp[(k + 4) * P_ + p];
            float w5 = Wp[(k + 5) * P_ + p];
            float w6 = Wp[(k + 6) * P_ + p];
            float w7 = Wp[(k + 7) * P_ + p];
            float4 xA = *(const float4*)(xr + k);
            float4 xB = *(const float4*)(xr + k + 4);
            a0 += xA.x * w0; a1 += xA.y * w1; a2 += xA.z * w2; a3 += xA.w * w3;
            a0 += xB.x * w4; a1 += xB.y * w5; a2 += xB.z * w6; a3 += xB.w * w7;
        }
        float a = (a0 + a1) + (a2 + a3) + bp[p];
        // fast tanh: 1 - 2/(e^{2a}+1); inf-safe at both extremes
        float e  = __expf(2.0f * a);
        float ph = (1.0f - __fdividef(2.0f, e + 1.0f)) * PIF;
        const int row = row0 + rr;
        const int idx = row * P_ + p;
        phases_out[idx] = ph;
        float s, c;
        __sincosf(ph, &s, &c);
        if (phasorMode == 0) {
            ((float2*)phasor_out)[idx] = make_float2(c, s);
        } else if (phasorMode == 1) {
            phasor_out[idx] = c;
        }
        if (hasPT) {
            const int b = row >> 10, l = row & (L_ - 1);
            const size_t ti = (size_t)(b * P_ + p) * L_ + l;
            if (mode == 1) phasorT[ti] = c;                       // cos only
            else ((float2*)phasorT)[ti] = make_float2(c, s);
        }
    }
}

// ---------------------------------------------------------------------------
// Chunk partials (uniform 64 iters/block — no tail). mode 1: cos-only float2
// partial (halves FLOPs + S traffic vs round-0 float4). 1024 blocks x 128.
// ---------------------------------------------------------------------------
__global__ __launch_bounds__(128) void k_partial(
    const float* __restrict__ values, const float* __restrict__ phases,
    const float* __restrict__ phasorT, float* __restrict__ S,
    int mode, int hasPT)
{
    const int blk = blockIdx.x;                  // b*P_*C_ + p*C_ + c
    const int c = blk & (C_ - 1);
    const int p = (blk >> 4) & (P_ - 1);
    const int b = blk >> 9;
    const int tid = threadIdx.x;                 // 0..127
    const int l0 = c * CL_;
    const int bp = b * P_ + p;

    __shared__ float pcs[2 * CL_];               // mode1: 64 fl; mode0: 64 f2
    if (hasPT) {
        if (mode == 1) {
            if (tid < CL_ / 4)
                ((float4*)pcs)[tid] =
                    ((const float4*)(phasorT + (size_t)bp * L_ + l0))[tid];
        } else {
            if (tid < CL_ / 2)
                ((float4*)pcs)[tid] = ((const float4*)
                    ((const float2*)phasorT + (size_t)bp * L_ + l0))[tid];
        }
    } else {
        if (tid < CL_) {
            float ph = phases[(b * L_ + l0 + tid) * P_ + p];
            if (mode == 1) pcs[tid] = __cosf(ph);
            else ((float2*)pcs)[tid] = make_float2(__cosf(ph), __sinf(ph));
        }
    }
    __syncthreads();

    const float2* vp = (const float2*)(values + (size_t)(b * L_ + l0) * D_) + tid;

    if (mode == 1) {
        float sx = 0.f, sy = 0.f;
        #pragma unroll
        for (int i = 0; i < CL_; ++i) {
            float pc = pcs[i];                   // same-addr LDS broadcast
            float2 v = vp[(size_t)i * (D_/2)];   // coalesced 8B/lane (L2)
            sx += pc * v.x;
            sy += pc * v.y;
        }
        ((float2*)S)[((size_t)bp * C_ + c) * (D_/2) + tid] = make_float2(sx, sy);
    } else {
        float4 a = make_float4(0.f, 0.f, 0.f, 0.f);
        #pragma unroll
        for (int i = 0; i < CL_; ++i) {
            float2 q = ((float2*)pcs)[i];
            float2 v = vp[(size_t)i * (D_/2)];
            a.x += q.x * v.x; a.y += q.y * v.x;
            a.z += q.x * v.y; a.w += q.y * v.y;
        }
        ((float4*)S)[((size_t)bp * C_ + c) * (D_/2) + tid] = a;
    }
}

// ---------------------------------------------------------------------------
// Scan: carry = sum of <=15 chunk partials (independent loads), then uniform
// 64-step running sum + NT store. 1024 blocks x 128.
// ---------------------------------------------------------------------------
__global__ __launch_bounds__(128) void k_scan(
    const float* __restrict__ values, const float* __restrict__ phases,
    const float* __restrict__ phasorT, const float* __restrict__ S,
    float* __restrict__ mem, int mode, int hasPT)
{
    const int blk = blockIdx.x;
    const int c = blk & (C_ - 1);
    const int p = (blk >> 4) & (P_ - 1);
    const int b = blk >> 9;
    const int tid = threadIdx.x;
    const int l0 = c * CL_;
    const int bp = b * P_ + p;

    __shared__ float pcs[2 * CL_];
    if (hasPT) {
        if (mode == 1) {
            if (tid < CL_ / 4)
                ((float4*)pcs)[tid] =
                    ((const float4*)(phasorT + (size_t)bp * L_ + l0))[tid];
        } else {
            if (tid < CL_ / 2)
                ((float4*)pcs)[tid] = ((const float4*)
                    ((const float2*)phasorT + (size_t)bp * L_ + l0))[tid];
        }
    } else {
        if (tid < CL_) {
            float ph = phases[(b * L_ + l0 + tid) * P_ + p];
            if (mode == 1) pcs[tid] = __cosf(ph);
            else ((float2*)pcs)[tid] = make_float2(__cosf(ph), __sinf(ph));
        }
    }

    const float2* vp = (const float2*)(values + (size_t)(b * L_ + l0) * D_) + tid;

    if (mode == 1) {
        float cx = 0.f, cz = 0.f;
        const float2* Sb = (const float2*)S + (size_t)bp * C_ * (D_/2) + tid;
        for (int cc = 0; cc < c; ++cc) {         // <=15 independent loads
            float2 s = Sb[(size_t)cc * (D_/2)];
            cx += s.x; cz += s.y;
        }
        __syncthreads();
        nvf2* dst = (nvf2*)mem + ((size_t)(b * L_ + l0) * P_ + p) * (D_/2) + tid;
        const size_t st = (size_t)P_ * (D_/2);   // row stride in float2
        #pragma unroll
        for (int i = 0; i < CL_; ++i) {
            float pc = pcs[i];
            float2 v = vp[(size_t)i * (D_/2)];   // L2-hot (read by partial)
            cx += pc * v.x;
            cz += pc * v.y;
            nvf2 o = { cx, cz };
            __builtin_nontemporal_store(o, dst + (size_t)i * st);
        }
    } else {
        float4 carry = make_float4(0.f, 0.f, 0.f, 0.f);
        const float4* Sb = (const float4*)S + (size_t)bp * C_ * (D_/2) + tid;
        for (int cc = 0; cc < c; ++cc) {
            float4 s = Sb[(size_t)cc * (D_/2)];
            carry.x += s.x; carry.y += s.y; carry.z += s.z; carry.w += s.w;
        }
        __syncthreads();
        nvf4* dst = (nvf4*)mem + ((size_t)(b * L_ + l0) * P_ + p) * (D_/2) + tid;
        const size_t st = (size_t)P_ * (D_/2);
        #pragma unroll
        for (int i = 0; i < CL_; ++i) {
            float2 q = ((float2*)pcs)[i];
            float2 v = vp[(size_t)i * (D_/2)];
            carry.x += q.x * v.x; carry.y += q.y * v.x;
            carry.z += q.x * v.y; carry.w += q.y * v.y;
            nvf4 o = { carry.x, carry.y, carry.z, carry.w };
            __builtin_nontemporal_store(o, dst + (size_t)i * st);
        }
    }
}

// ---------------------------------------------------------------------------
// Path B parachute (small ws): carry recomputed from values/phases via L2.
// ---------------------------------------------------------------------------
__global__ __launch_bounds__(128) void k_scan_rc(
    const float* __restrict__ values, const float* __restrict__ phases,
    float* __restrict__ mem, int mode)
{
    const int blk = blockIdx.x;
    const int c = blk & (C_ - 1);
    const int p = (blk >> 4) & (P_ - 1);
    const int b = blk >> 9;
    const int tid = threadIdx.x;
    const int l0 = c * CL_;

    const float2* vb = (const float2*)(values + (size_t)b * L_ * D_);
    float4 carry = make_float4(0.f, 0.f, 0.f, 0.f);
    for (int l = 0; l < l0; ++l) {
        float ph = phases[(b * L_ + l) * P_ + p];
        float s = __sinf(ph), cs = __cosf(ph);
        float2 v = vb[l * (D_/2) + tid];
        carry.x += cs * v.x; carry.y += s * v.x;
        carry.z += cs * v.y; carry.w += s * v.y;
    }
    for (int i = 0; i < CL_; ++i) {
        const int l = l0 + i;
        float ph = phases[(b * L_ + l) * P_ + p];
        float s = __sinf(ph), cs = __cosf(ph);
        float2 v = vb[l * (D_/2) + tid];
        carry.x += cs * v.x; carry.y += s * v.x;
        carry.z += cs * v.y; carry.w += s * v.y;
        const size_t rowIdx = (size_t)(b * L_ + l) * P_ + p;
        if (mode == 0) ((float4*)mem)[rowIdx * (D_/2) + tid] = carry;
        else ((float2*)mem)[rowIdx * (D_/2) + tid] = make_float2(carry.x, carry.z);
    }
}

extern "C" void kernel_launch(void* const* d_in, const int* in_sizes, int n_in,
                              void* d_out, int out_size, void* d_ws, size_t ws_size,
                              hipStream_t stream) {
    const float* x  = (const float*)d_in[0];
    const float* Wp = (const float*)d_in[1];
    const float* bp = (const float*)d_in[2];
    const float* Wv = (const float*)d_in[3];
    const float* bv = (const float*)d_in[4];
    float* out = (float*)d_out;

    const size_t nMemF = (size_t)2 * B_ * L_ * P_ * D_;  // 33554432 (interleaved)
    const size_t nMemR = (size_t)B_ * L_ * P_ * D_;      // 16777216 (real only)
    const size_t nPh   = (size_t)B_ * L_ * P_;           // 65536

    // Output layout mode by out_size. Round-2/3 counter evidence: scan
    // WRITE_SIZE = 64 MiB = nMemR*4B => harness runs mode 1.
    int mode; size_t memFloats;
    if ((size_t)out_size >= nMemF + 3 * nPh) { mode = 0; memFloats = nMemF; }
    else                                     { mode = 1; memFloats = nMemR; }
    const bool memFits      = (size_t)out_size >= memFloats;
    const bool phasesInOut  = (size_t)out_size >= memFloats + nPh;
    const bool phasorsInOut =
        (size_t)out_size >= memFloats + nPh + (mode == 0 ? 2 * nPh : nPh);

    // ws layout: values | phasesWs | S | phasorT
    const size_t valB = (size_t)B_ * L_ * D_ * sizeof(float);                // 2 MB
    const size_t phB  = nPh * sizeof(float);                                 // 256 KB
    const size_t sB   = (size_t)B_ * P_ * C_ * (D_/2) * sizeof(float4);      // 2 MB (mode0 max)
    const size_t ptB  = nPh * (mode == 0 ? sizeof(float2) : sizeof(float));  // 512/256 KB
    float* values   = (float*)d_ws;
    float* phasesWs = (float*)((char*)d_ws + valB);
    float* S        = (float*)((char*)d_ws + valB + phB);
    float* phasorT  = (float*)((char*)d_ws + valB + phB + sB);

    float* phasesPtr = phasesInOut ? (out + memFloats)
                     : (ws_size >= valB + phB ? phasesWs : nullptr);
    if (phasesPtr == nullptr) return;            // unreachable (ws verified big enough)

    float* phasorPtr = phasorsInOut ? (out + memFloats + nPh) : nullptr;
    const int phasorMode = phasorsInOut ? mode : 2;

    const bool pathA = ws_size >= valB + phB + sB;           // partials fit
    const int  hasPT = (pathA && ws_size >= valB + phB + sB + ptB) ? 1 : 0;

    k_proj3<<<NROW / 2 + NROW / 8, 256, 0, stream>>>(
        x, Wp, bp, Wv, bv, values, phasesPtr, phasorPtr, phasorT,
        phasorMode, mode, hasPT);
    if (!memFits) return;

    if (pathA) {
        k_partial<<<B_ * P_ * C_, 128, 0, stream>>>(values, phasesPtr, phasorT,
                                                    S, mode, hasPT);
        k_scan<<<B_ * P_ * C_, 128, 0, stream>>>(values, phasesPtr, phasorT,
                                                 S, out, mode, hasPT);
    } else {
        k_scan_rc<<<B_ * P_ * C_, 128, 0, stream>>>(values, phasesPtr, out, mode);
    }
}